// Round 15
// baseline (177.642 us; speedup 1.0000x reference)
//
#include <hip/hip_runtime.h>

#define N_NODES 8192
#define DIM 32
#define NCLS 16
#define NCOLC 36                /* packed partial-C columns (36..47 structurally zero) */
#define NKT (N_NODES / 32)      /* 256 k-tiles per row stripe */
#define RT_STRIDE ((size_t)NKT * 512)
#define PITCH 520               /* LDS row pitch in bf16 elems (1040B) */
#define KSEG 512                /* k per supertile (k_mmc) */
#define SPLITS 8                /* Cpart splits for all passes */

typedef __bf16 bf16x8 __attribute__((ext_vector_type(8)));
typedef float f32x4 __attribute__((ext_vector_type(4)));

__device__ inline unsigned short f2bf(float f) {
  unsigned u = __float_as_uint(f);
  u = u + 0x7FFFu + ((u >> 16) & 1u);  // RNE
  return (unsigned short)(u >> 16);
}

__device__ inline float artanh_pos(float x) {
  x = fminf(x, 1.0f - 1e-7f);
  return 0.5f * logf((1.0f + x) / (1.0f - x));
}

// G: [nt][3 colblk][16 col][32 n]
__device__ inline size_t g_tile_idx(int c, int n) {
  return ((size_t)(n >> 5) * 3 + (c >> 4)) * 512 + (size_t)((c & 15) * 32 + (n & 31));
}
// L: [nt][16 col][32 n]
__device__ inline size_t l_tile_idx(int c, int n) {
  return (size_t)(n >> 5) * 512 + (size_t)(c * 32 + (n & 31));
}

// ---------------- FUSED pipelined: A fp32 -> bf16 tiles + mm pass 1 ----------------
// R14 structure; A loads are PLAIN CACHED (single-variable test vs R14's NT loads);
// Abf stores stay non-temporal.
__global__ __launch_bounds__(256) void k_mmc(const float* __restrict__ A,
                                             const unsigned short* __restrict__ GT,
                                             unsigned short* __restrict__ Abf,
                                             float* __restrict__ Cpart) {
  __shared__ __align__(16) unsigned short buf0[16 * PITCH];
  __shared__ __align__(16) unsigned short buf1[16 * PITCH];
  float* lds_r = (float*)buf0;
  const int t = threadIdx.x;
  const int rt = blockIdx.x >> 3;
  const int q = blockIdx.x & 7;
  const int ks0 = 2 * q, ks1 = 2 * q + 1;
  const int lane = t & 63;
  const int w = t >> 6;
  const int lr = lane & 15;
  const int lkg = lane >> 4;
  const int vrow = t >> 7;
  const int vk = (t & 127) * 4;
  const int poff = lr * 32 + lkg * 8;

  const float* srcbase = A + (size_t)(rt * 16) * N_NODES;

  f32x4 r0[8];
#pragma unroll
  for (int v = 0; v < 8; v++)
    r0[v] = *(const f32x4*)(srcbase + (size_t)(2 * v + vrow) * N_NODES + ks0 * KSEG + vk);
#pragma unroll
  for (int v = 0; v < 8; v++) {
    uint2 o;
    o.x = f2bf(r0[v][0]) | ((unsigned)f2bf(r0[v][1]) << 16);
    o.y = f2bf(r0[v][2]) | ((unsigned)f2bf(r0[v][3]) << 16);
    *(uint2*)(buf0 + (2 * v + vrow) * PITCH + vk) = o;
  }
  __syncthreads();

  f32x4 r1[8];
#pragma unroll
  for (int v = 0; v < 8; v++)
    r1[v] = *(const f32x4*)(srcbase + (size_t)(2 * v + vrow) * N_NODES + ks1 * KSEG + vk);

  f32x4 acc[3];
#pragma unroll
  for (int nf = 0; nf < 3; nf++) acc[nf] = (f32x4){0.f, 0.f, 0.f, 0.f};
#pragma unroll
  for (int i = 0; i < 4; i++) {
    const int kt2 = 4 * w + i;
    bf16x8 a = *(const bf16x8*)(buf0 + lr * PITCH + kt2 * 32 + lkg * 8);
#pragma unroll
    for (int nf = 0; nf < 3; nf++) {
      bf16x8 b = *(const bf16x8*)(GT + ((size_t)(ks0 * 16 + kt2) * 3 + nf) * 512 + poff);
      acc[nf] = __builtin_amdgcn_mfma_f32_16x16x32_bf16(a, b, acc[nf], 0, 0, 0);
    }
  }
  {
    unsigned short* dst = Abf + (size_t)(rt * 16 + ks0) * 8192;
#pragma unroll
    for (int u = 0; u < 4; u++) {
      const int p = u * 256 + t;
      const int kt = p >> 6;
      const int qq = p & 63;
      bf16x8 val = *(const bf16x8*)(buf0 + (qq >> 2) * PITCH + kt * 32 + (qq & 3) * 8);
      __builtin_nontemporal_store(val, (bf16x8*)(dst + (size_t)p * 8));
    }
  }

#pragma unroll
  for (int v = 0; v < 8; v++) {
    uint2 o;
    o.x = f2bf(r1[v][0]) | ((unsigned)f2bf(r1[v][1]) << 16);
    o.y = f2bf(r1[v][2]) | ((unsigned)f2bf(r1[v][3]) << 16);
    *(uint2*)(buf1 + (2 * v + vrow) * PITCH + vk) = o;
  }
  __syncthreads();

#pragma unroll
  for (int i = 0; i < 4; i++) {
    const int kt2 = 4 * w + i;
    bf16x8 a = *(const bf16x8*)(buf1 + lr * PITCH + kt2 * 32 + lkg * 8);
#pragma unroll
    for (int nf = 0; nf < 3; nf++) {
      bf16x8 b = *(const bf16x8*)(GT + ((size_t)(ks1 * 16 + kt2) * 3 + nf) * 512 + poff);
      acc[nf] = __builtin_amdgcn_mfma_f32_16x16x32_bf16(a, b, acc[nf], 0, 0, 0);
    }
  }
  {
    unsigned short* dst = Abf + (size_t)(rt * 16 + ks1) * 8192;
#pragma unroll
    for (int u = 0; u < 4; u++) {
      const int p = u * 256 + t;
      const int kt = p >> 6;
      const int qq = p & 63;
      bf16x8 val = *(const bf16x8*)(buf1 + (qq >> 2) * PITCH + kt * 32 + (qq & 3) * 8);
      __builtin_nontemporal_store(val, (bf16x8*)(dst + (size_t)p * 8));
    }
  }
  __syncthreads();

#pragma unroll
  for (int nf = 0; nf < 3; nf++)
#pragma unroll
    for (int j = 0; j < 4; j++)
      lds_r[(w * 16 + lkg * 4 + j) * 48 + nf * 16 + lr] = acc[nf][j];
  __syncthreads();
  for (int e = t; e < 16 * 36; e += 256) {
    const int row = e / 36;
    const int col = e % 36;
    float s = lds_r[row * 48 + col] + lds_r[768 + row * 48 + col] +
              lds_r[1536 + row * 48 + col] + lds_r[2304 + row * 48 + col];
    Cpart[((size_t)q * N_NODES + rt * 16 + row) * NCOLC + col] = s;
  }
}

// ---------------- pre: mobius_matvec + gamma -> G tiles ----------------
__device__ inline void pre_math(const float* __restrict__ Wl, const float x[DIM],
                                unsigned short* __restrict__ GT, int n) {
  float xn2 = 0.f;
#pragma unroll
  for (int i = 0; i < DIM; i++) xn2 += x[i] * x[i];
  float xn = sqrtf(fmaxf(xn2, 1e-30f));
  float mx[DIM];
#pragma unroll
  for (int j = 0; j < DIM; j++) mx[j] = 0.f;
  for (int i = 0; i < DIM; i++) {
    float xi = x[i];
#pragma unroll
    for (int j = 0; j < DIM; j++) mx[j] = fmaf(xi, Wl[i * DIM + j], mx[j]);
  }
  float mxn2 = 0.f;
#pragma unroll
  for (int j = 0; j < DIM; j++) mxn2 += mx[j] * mx[j];
  float mxn = sqrtf(fmaxf(mxn2, 1e-30f));
  float t = tanhf(mxn / xn * artanh_pos(xn));
  float sc = t / mxn;
  float xw[DIM];
  float x2n = 0.f;
#pragma unroll
  for (int j = 0; j < DIM; j++) { xw[j] = sc * mx[j]; x2n += xw[j] * xw[j]; }
  float gamma = 2.0f / fmaxf(1.0f - x2n, 1e-15f);
#pragma unroll
  for (int c = 0; c < DIM; c++) GT[g_tile_idx(c, n)] = f2bf(gamma * xw[c]);
  GT[g_tile_idx(32, n)] = f2bf(gamma - 1.0f);
  GT[g_tile_idx(33, n)] = f2bf(1.0f);
#pragma unroll
  for (int c = DIM + 2; c < 48; c++) GT[g_tile_idx(c, n)] = 0;
}

__global__ void k_pre1(const float* __restrict__ X, const float* __restrict__ W,
                       unsigned short* __restrict__ GT) {
  __shared__ float Wl[DIM * DIM];
  for (int i = threadIdx.x; i < DIM * DIM; i += blockDim.x) Wl[i] = W[i];
  __syncthreads();
  const int n = blockIdx.x * blockDim.x + threadIdx.x;
  float x[DIM];
#pragma unroll
  for (int i = 0; i < DIM; i += 4) {
    float4 v = *(const float4*)(X + (size_t)n * DIM + i);
    x[i] = v.x; x[i + 1] = v.y; x[i + 2] = v.z; x[i + 3] = v.w;
  }
  pre_math(Wl, x, GT, n);
}

// ---------------- parallel split-reduce (4 subs x 2 splits) + post tail ----------------
__device__ inline void par_reduce(const float* __restrict__ Cpart, int n, int sub, int nl,
                                  float red[4][64][NCOLC]) {
  float acc[NCOLC];
#pragma unroll
  for (int c = 0; c < NCOLC; c++) acc[c] = 0.f;
#pragma unroll
  for (int si = 0; si < 2; si++) {
    const int s = sub * 2 + si;
    const float4* p = (const float4*)(Cpart + ((size_t)s * N_NODES + n) * NCOLC);
#pragma unroll
    for (int qq = 0; qq < NCOLC / 4; qq++) {
      float4 v = p[qq];
      acc[qq * 4 + 0] += v.x; acc[qq * 4 + 1] += v.y;
      acc[qq * 4 + 2] += v.z; acc[qq * 4 + 3] += v.w;
    }
  }
#pragma unroll
  for (int c = 0; c < NCOLC; c++) red[sub][nl][c] = acc[c];
}

__device__ inline void post_tail(const float acc[NCOLC], float xo[DIM]) {
  float denom = acc[32];
  float alpha = acc[33];
  denom = (denom >= 0.f) ? fmaxf(denom, 1e-10f) : fminf(denom, -1e-10f);
  float inv = 1.0f / denom;
  float v[DIM];
  float vn2 = 0.f;
#pragma unroll
  for (int c = 0; c < DIM; c++) { v[c] = acc[c] * inv; vn2 += v[c] * v[c]; }
  float vn = sqrtf(fmaxf(vn2, 1e-30f));
  float un = alpha * 0.5f * artanh_pos(vn);
  float su = un / vn;
  float r[DIM];
  float rn2 = 0.f;
#pragma unroll
  for (int c = 0; c < DIM; c++) { r[c] = fmaxf(su * v[c], 0.f); rn2 += r[c] * r[c]; }
  float rn = sqrtf(fmaxf(rn2, 1e-30f));
  float so = tanhf(rn) / rn;
#pragma unroll
  for (int c = 0; c < DIM; c++) xo[c] = so * r[c];
}

__global__ __launch_bounds__(256) void k_postpre(const float* __restrict__ Cpart,
                                                 const float* __restrict__ W,
                                                 unsigned short* __restrict__ GT) {
  __shared__ float Wl[DIM * DIM];
  __shared__ float red[4][64][NCOLC];
  const int t = threadIdx.x;
  const int nl = t & 63;
  const int sub = t >> 6;
  for (int i = t; i < DIM * DIM; i += 256) Wl[i] = W[i];
  const int n = blockIdx.x * 64 + nl;
  par_reduce(Cpart, n, sub, nl, red);
  __syncthreads();
  if (sub == 0) {
    float acc[NCOLC];
#pragma unroll
    for (int c = 0; c < NCOLC; c++)
      acc[c] = ((red[0][nl][c] + red[1][nl][c]) + red[2][nl][c]) + red[3][nl][c];
    float x[DIM];
    post_tail(acc, x);
    pre_math(Wl, x, GT, n);
  }
}

__global__ __launch_bounds__(256) void k_postlogits(const float* __restrict__ Cpart,
                                                    const float* __restrict__ Wl_g,
                                                    const float* __restrict__ B_g,
                                                    unsigned short* __restrict__ LT) {
  __shared__ float Wc[DIM * NCLS];
  __shared__ float Bc[NCLS * DIM];
  __shared__ float an_s[NCLS], lam_s[NCLS], b2_s[NCLS];
  __shared__ float red[4][64][NCOLC];
  const int t = threadIdx.x;
  const int nl = t & 63;
  const int sub = t >> 6;
  for (int i = t; i < DIM * NCLS; i += 256) { Wc[i] = Wl_g[i]; Bc[i] = B_g[i]; }
  __syncthreads();
  if (t < NCLS) {
    int c = t;
    float b2 = 0.f, w2 = 0.f;
    for (int d = 0; d < DIM; d++) {
      b2 += Bc[c * DIM + d] * Bc[c * DIM + d];
      w2 += Wc[d * NCLS + c] * Wc[d * NCLS + c];
    }
    b2_s[c] = b2;
    an_s[c] = fmaxf(sqrtf(w2), 1e-10f);
    lam_s[c] = 2.0f / fmaxf(1.0f - b2, 1e-15f);
  }
  const int n = blockIdx.x * 64 + nl;
  par_reduce(Cpart, n, sub, nl, red);
  __syncthreads();
  if (sub == 0) {
    float acc[NCOLC];
#pragma unroll
    for (int c = 0; c < NCOLC; c++)
      acc[c] = ((red[0][nl][c] + red[1][nl][c]) + red[2][nl][c]) + red[3][nl][c];
    float x[DIM];
    post_tail(acc, x);
    float y2 = 0.f;
#pragma unroll
    for (int i = 0; i < DIM; i++) y2 += x[i] * x[i];
    for (int c = 0; c < NCLS; c++) {
      float b2 = b2_s[c];
      float bx = 0.f;
      for (int d = 0; d < DIM; d++) bx += Bc[c * DIM + d] * x[d];
      float xy = -bx;
      float f1 = 1.0f + 2.0f * xy + y2;
      float f2 = 1.0f - b2;
      float den = fmaxf(1.0f + 2.0f * xy + b2 * y2, 1e-15f);
      float invden = 1.0f / den;
      float zn2 = 0.f, za = 0.f;
      for (int d = 0; d < DIM; d++) {
        float z = (f1 * (-Bc[c * DIM + d]) + f2 * x[d]) * invden;
        zn2 += z * z;
        za += z * Wc[d * NCLS + c];
      }
      float zn = fmaxf(sqrtf(fmaxf(zn2, 1e-30f)), 1e-10f);
      float dist = asinhf(2.0f * za / ((1.0f - zn * zn) * an_s[c]));
      LT[l_tile_idx(c, n)] = f2bf(lam_s[c] * an_s[c] * dist);
    }
  }
}

// ---------------- MFMA matmul over Abf tiles (passes 2/3), 1024-k per block ----------------
template <int NF>
__global__ __launch_bounds__(256) void k_mm(const unsigned short* __restrict__ A,
                                            const unsigned short* __restrict__ BT,
                                            float* __restrict__ Cpart) {
  const int lane = threadIdx.x & 63;
  const int wid = threadIdx.x >> 6;
  const int r0 = blockIdx.x * 128 + wid * 32;
  const int kt0 = blockIdx.y * 32;
  const int lr = lane & 15;
  const int lkg = lane >> 4;
  const int poff = lr * 32 + lkg * 8;
  const int BS = (NF == 3) ? 3 : 1;
  f32x4 acc[2][NF];
#pragma unroll
  for (int m = 0; m < 2; m++)
#pragma unroll
    for (int nf = 0; nf < NF; nf++) acc[m][nf] = (f32x4){0.f, 0.f, 0.f, 0.f};
  const unsigned short* pa0 = A + ((size_t)(r0 >> 4) * NKT + kt0) * 512 + poff;
  const unsigned short* pa1 = pa0 + RT_STRIDE;
  const unsigned short* pbB = BT + (size_t)kt0 * BS * 512 + poff;
#pragma unroll 4
  for (int kt = 0; kt < 32; kt++) {
    bf16x8 a0 = *(const bf16x8*)(pa0 + (size_t)kt * 512);
    bf16x8 a1 = *(const bf16x8*)(pa1 + (size_t)kt * 512);
#pragma unroll
    for (int nf = 0; nf < NF; nf++) {
      bf16x8 b = *(const bf16x8*)(pbB + (size_t)(kt * BS + nf) * 512);
      acc[0][nf] = __builtin_amdgcn_mfma_f32_16x16x32_bf16(a0, b, acc[0][nf], 0, 0, 0);
      acc[1][nf] = __builtin_amdgcn_mfma_f32_16x16x32_bf16(a1, b, acc[1][nf], 0, 0, 0);
    }
  }
  const int NCOL = (NF == 3) ? NCOLC : NF * 16;
  float* Cb = Cpart + (size_t)blockIdx.y * N_NODES * NCOL;
#pragma unroll
  for (int m = 0; m < 2; m++)
#pragma unroll
    for (int nf = 0; nf < NF; nf++) {
      if (NF == 3 && nf == 2 && lr >= 4) continue;
#pragma unroll
      for (int j = 0; j < 4; j++) {
        int row = r0 + m * 16 + lkg * 4 + j;
        int col = nf * 16 + lr;
        Cb[(size_t)row * NCOL + col] = acc[m][nf][j];
      }
    }
}

// ---------------- final splitK reduce into d_out ----------------
template <int TOTAL>
__global__ void k_red(const float* __restrict__ part, float* __restrict__ outb) {
  int i = blockIdx.x * blockDim.x + threadIdx.x;
  if (i < TOTAL) {
    float s = 0.f;
#pragma unroll
    for (int qq = 0; qq < SPLITS; qq++) s += part[(size_t)qq * TOTAL + i];
    outb[i] = s;
  }
}

extern "C" void kernel_launch(void* const* d_in, const int* in_sizes, int n_in,
                              void* d_out, int out_size, void* d_ws, size_t ws_size,
                              hipStream_t stream) {
  (void)in_sizes; (void)n_in; (void)out_size; (void)ws_size;
  const float* X  = (const float*)d_in[0];
  const float* A  = (const float*)d_in[1];
  const float* W1 = (const float*)d_in[2];
  const float* W2 = (const float*)d_in[3];
  const float* WL = (const float*)d_in[4];
  const float* PK = (const float*)d_in[5];
  float* out = (float*)d_out;

  char* ws = (char*)d_ws;
  unsigned short* Abf = (unsigned short*)ws;                  // 134,217,728 B (tiled)
  unsigned short* GT  = (unsigned short*)(ws + 134217728);    //     786,432 B (tiled)
  float* Cpart        = (float*)(ws + 135004160);             //   9,437,184 B (8 splits)
  unsigned short* LT  = (unsigned short*)(ws + 153878528);    //     262,144 B (tiled)

  // layer 1: fused pipelined convert + mm1 (plain cached A loads, NT Abf stores)
  k_pre1<<<N_NODES / 64, 64, 0, stream>>>(X, W1, GT);
  k_mmc<<<4096, 256, 0, stream>>>(A, GT, Abf, Cpart);
  k_postpre<<<N_NODES / 64, 256, 0, stream>>>(Cpart, W2, GT);

  // layer 2
  k_mm<3><<<dim3(64, 8), 256, 0, stream>>>(Abf, GT, Cpart);
  k_postlogits<<<N_NODES / 64, 256, 0, stream>>>(Cpart, WL, PK, LT);

  // logits aggregation
  k_mm<1><<<dim3(64, 8), 256, 0, stream>>>(Abf, LT, Cpart);
  k_red<N_NODES * NCLS><<<(N_NODES * NCLS + 255) / 256, 256, 0, stream>>>(Cpart, out);
}